// Round 7
// baseline (287.336 us; speedup 1.0000x reference)
//
#include <hip/hip_runtime.h>
#include <stdint.h>
#include <stddef.h>

// EuclideanAttention MI355X, round 7.
// - flash: NO LDS, NO barriers. K/V fragments loaded directly from global
//   (permuted VT layout makes PV B-frags contiguous 16B); the 32KB chunk is
//   L1-resident and broadcast-served to all 8 waves/CU. Free-running K-loop
//   (hipBLASLt-style), latency hidden by 2 waves/SIMD + MFMA.
// - GEMMs: round-5 measured-best BK=64 two-stage staging; round-6 epilogues
//   (no q^2 sumsq -- the q^2 softmax shift cancels).

#define LOG2E 1.44269504088896f

typedef __attribute__((ext_vector_type(8))) short bf16x8;
typedef __attribute__((ext_vector_type(4))) float f32x4;
typedef __attribute__((ext_vector_type(4))) unsigned short u16x4;

__device__ __forceinline__ unsigned short f2b(float f) {
  union { float f; unsigned int u; } x; x.f = f;
  unsigned int u = x.u;
  u += 0x7fffu + ((u >> 16) & 1u);   // RNE
  return (unsigned short)(u >> 16);
}
__device__ __forceinline__ float b2f(unsigned short s) {
  union { unsigned int u; float f; } x; x.u = ((unsigned int)s) << 16;
  return x.f;
}
__device__ __forceinline__ unsigned int fbits(float f) {
  union { float f; unsigned int u; } x; x.f = f; return x.u;
}

// async global->LDS, 16B per lane. LDS dest = wave-uniform base + lane*16.
#define GLD_LDS(g, l) __builtin_amdgcn_global_load_lds( \
    (const __attribute__((address_space(1))) void*)(g), \
    (__attribute__((address_space(3))) void*)(l), 16, 0, 0)

// ------------------------------------------------- prep: W transpose + X cvt
__global__ void prep_kernel(const float* __restrict__ X,
                            const float* __restrict__ wq, const float* __restrict__ wk,
                            const float* __restrict__ wv, const float* __restrict__ wo,
                            unsigned short* __restrict__ Xb,
                            unsigned short* __restrict__ WTqkv, unsigned short* __restrict__ WTo) {
  int z = blockIdx.z;
  if (z == 4) {
    size_t base = ((size_t)(blockIdx.y * 16 + blockIdx.x)) * 16384;
    #pragma unroll
    for (int j = 0; j < 16; ++j) {
      size_t i = base + (size_t)(j * 256 + threadIdx.x) * 4;
      f32x4 v = *(const f32x4*)&X[i];
      u16x4 o;
      #pragma unroll
      for (int k = 0; k < 4; ++k) o[k] = f2b(v[k]);
      *(u16x4*)&Xb[i] = o;
    }
    return;
  }
  __shared__ float tile[64][65];
  const float* src = (z == 0) ? wq : (z == 1) ? wk : (z == 2) ? wv : wo;
  unsigned short* dst = (z < 3) ? (WTqkv + (size_t)z * 1024 * 1024) : WTo;
  int k0 = blockIdx.y * 64, n0 = blockIdx.x * 64;
  int rr = threadIdx.x >> 6, cc = threadIdx.x & 63;
  #pragma unroll
  for (int p = 0; p < 16; ++p) {
    int row = p * 4 + rr;
    tile[row][cc] = src[(size_t)(k0 + row) * 1024 + n0 + cc];
  }
  __syncthreads();
  #pragma unroll
  for (int p = 0; p < 16; ++p) {
    int row = p * 4 + rr;                       // n offset
    dst[(size_t)(n0 + row) * 1024 + k0 + cc] = f2b(tile[cc][row]);
  }
}

// -------------------------------------------------------------- QKV GEMM
// C[4096,3072] = X @ [wq|wk|wv] + bias. 128x128 tile, BK=64 two-stage,
// 3 blocks/CU. K epilogue emits pre-scaled ||row||^2 (* log2e/T). V epilogue
// LDS-transposes into permuted VT (pos = G*32+q4*8+sub*4+i) with coalesced writes.
__global__ __launch_bounds__(256, 3) void gemm_qkv_kernel(
    const unsigned short* __restrict__ X, const unsigned short* __restrict__ WT,
    const float* __restrict__ bq, const float* __restrict__ bk, const float* __restrict__ bv,
    const float* __restrict__ temp,
    unsigned short* __restrict__ Qb, unsigned short* __restrict__ Kb,
    unsigned short* __restrict__ VTo, float* __restrict__ ks2) {
  __shared__ __align__(16) unsigned short smem[16896];   // As(8192) Bs(8192) | Vt alias
  unsigned short* As = smem;            // [kh<2][row<128][32]
  unsigned short* Bs = smem + 8192;
  const int t = threadIdx.x, w = t >> 6, lane = t & 63;
  const int r = lane & 15, q4 = lane >> 4;
  const int m0 = blockIdx.y * 128, n0 = blockIdx.x * 128;
  const int wr = (w >> 1) * 64, wc = (w & 1) * 64;
  const unsigned short* Xg = X + (size_t)m0 * 1024;
  const unsigned short* Wg = WT + (size_t)n0 * 1024;
  f32x4 acc[4][4] = {};
  for (int k0 = 0; k0 < 1024; k0 += 64) {
    #pragma unroll
    for (int g = 0; g < 4; ++g) {
      int slot = g * 256 + t;
      int kh = slot >> 9, row = (slot >> 2) & 127, ko = (slot & 3) * 8;
      GLD_LDS(Xg + (size_t)row * 1024 + k0 + kh * 32 + ko, &As[(g * 256 + w * 64) * 8]);
      GLD_LDS(Wg + (size_t)row * 1024 + k0 + kh * 32 + ko, &Bs[(g * 256 + w * 64) * 8]);
    }
    __syncthreads();
    #pragma unroll
    for (int kh = 0; kh < 2; ++kh) {
      bf16x8 af[4], bfr[4];
      #pragma unroll
      for (int mf = 0; mf < 4; ++mf)
        af[mf] = *(const bf16x8*)&As[kh * 4096 + (wr + mf * 16 + r) * 32 + q4 * 8];
      #pragma unroll
      for (int nf = 0; nf < 4; ++nf)
        bfr[nf] = *(const bf16x8*)&Bs[kh * 4096 + (wc + nf * 16 + r) * 32 + q4 * 8];
      #pragma unroll
      for (int mf = 0; mf < 4; ++mf)
        #pragma unroll
        for (int nf = 0; nf < 4; ++nf)
          acc[mf][nf] = __builtin_amdgcn_mfma_f32_16x16x32_bf16(af[mf], bfr[nf], acc[mf][nf], 0, 0, 0);
    }
    __syncthreads();
  }
  const int nblk = n0 >> 10;
  if (nblk == 0) {
    // Q: plain bf16 store (q^2 shift cancels in softmax)
    const int nc0 = n0 & 1023;
    #pragma unroll
    for (int nf = 0; nf < 4; ++nf) {
      int n = nc0 + wc + nf * 16 + r;
      float bb = bq[n];
      #pragma unroll
      for (int mf = 0; mf < 4; ++mf) {
        int m = m0 + wr + mf * 16 + q4 * 4;
        f32x4 v = acc[mf][nf];
        #pragma unroll
        for (int i = 0; i < 4; ++i)
          Qb[(size_t)(m + i) * 1024 + n] = f2b(v[i] + bb);
      }
    }
  } else if (nblk == 1) {
    const float sc = LOG2E / temp[0];
    const int nc0 = n0 & 1023;
    float s2a[4][4] = {};
    #pragma unroll
    for (int nf = 0; nf < 4; ++nf) {
      int n = nc0 + wc + nf * 16 + r;
      float bb = bk[n];
      #pragma unroll
      for (int mf = 0; mf < 4; ++mf) {
        int m = m0 + wr + mf * 16 + q4 * 4;
        f32x4 v = acc[mf][nf];
        #pragma unroll
        for (int i = 0; i < 4; ++i) {
          unsigned short os = f2b(v[i] + bb);
          Kb[(size_t)(m + i) * 1024 + n] = os;
          float xb = b2f(os);
          s2a[mf][i] += xb * xb;          // sum of squares of the ROUNDED value
        }
      }
    }
    #pragma unroll
    for (int mf = 0; mf < 4; ++mf)
      #pragma unroll
      for (int i = 0; i < 4; ++i) {
        float v = s2a[mf][i];
        v += __shfl_xor(v, 1, 64);
        v += __shfl_xor(v, 2, 64);
        v += __shfl_xor(v, 4, 64);
        v += __shfl_xor(v, 8, 64);
        s2a[mf][i] = v * sc;
      }
    if (r == 0) {
      int hh = (nc0 + wc) >> 6;
      #pragma unroll
      for (int mf = 0; mf < 4; ++mf) {
        int m = m0 + wr + mf * 16 + q4 * 4;
        int bb2 = m >> 11, ss = m & 2047;
        #pragma unroll
        for (int i = 0; i < 4; ++i)
          ks2[(size_t)(bb2 * 16 + hh) * 2048 + ss + i] = s2a[mf][i];
      }
    }
  } else {
    // ---- V: LDS transpose -> permuted, coalesced VT writes (Vt aliases As/Bs)
    unsigned short* Vt = smem;          // [head<2][d<64][G<2 * pos<64], stride 132
    const int c0 = n0 - 2048;
    const int head = w & 1;             // == wc>>6
    #pragma unroll
    for (int nf = 0; nf < 4; ++nf) {
      int c = c0 + wc + nf * 16 + r;
      float bb = bv[c];
      int d = c & 63;
      #pragma unroll
      for (int mf = 0; mf < 4; ++mf) {
        int mloc = wr + mf * 16 + q4 * 4;     // 0..124
        int G = mloc >> 6;
        int k6 = mloc & 63;
        int pos = (k6 >> 5) * 32 + ((k6 & 15) >> 2) * 8 + ((k6 >> 4) & 1) * 4;
        f32x4 v = acc[mf][nf];
        u16x4 pk;
        #pragma unroll
        for (int i = 0; i < 4; ++i) pk[i] = f2b(v[i] + bb);
        *(u16x4*)&Vt[(head * 64 + d) * 132 + G * 64 + pos] = pk;
      }
    }
    __syncthreads();
    int row = t >> 1, ch = t & 1;
    int hd = row >> 6, dd = row & 63;
    int hglob = (c0 >> 6) + hd;
    int bb2 = m0 >> 11, s0 = m0 & 2047;
    unsigned short* dst = &VTo[((size_t)((bb2 * 16 + hglob) * 64 + dd)) * 2048 + s0 + ch * 64];
    const unsigned short* srcL = &Vt[(hd * 64 + dd) * 132 + ch * 64];
    #pragma unroll
    for (int k2 = 0; k2 < 16; ++k2)
      *(u16x4*)&dst[k2 * 4] = *(const u16x4*)&srcL[k2 * 4];
  }
}

// ---------------------------------------------------------------- flash
// Block = (bh, 128 q-rows), 4 waves x 32 rows, 64-key chunks. NO LDS, NO
// barriers: K/V fragments loaded directly from global each chunk (32KB chunk
// is L1-resident; all 8 waves/CU read identical addresses -> L1 broadcast).
// S^T = K.Q^T: C-frag doubles as PV A-operand (keys tau-permuted); VT global
// layout is pre-permuted so a PV B-frag is 16 contiguous bytes.
// p = exp2((2qk - k^2)*log2e/T)  (q^2 shift cancels; bounded by ~8)
__global__ __launch_bounds__(256, 2) void flash_kernel(
    const unsigned short* __restrict__ Qb, const unsigned short* __restrict__ Kb,
    const unsigned short* __restrict__ VT, const float* __restrict__ ks2,
    const float* __restrict__ temp, unsigned short* __restrict__ AO) {
  const int t = threadIdx.x, w = t >> 6, lane = t & 63;
  const int r = lane & 15, q4 = lane >> 4;
  const int bh = blockIdx.y, b = bh >> 4, h = bh & 15;
  const int q0 = blockIdx.x * 128;
  const float cc = 2.0f * LOG2E / temp[0];

  // Q fragments (B-operand: n=qrow=lane&15, k=q4*8+j), resident in VGPRs
  bf16x8 qf[2][2];
  #pragma unroll
  for (int mf = 0; mf < 2; ++mf) {
    int sq = q0 + w * 32 + mf * 16 + r;
    const unsigned short* qp = Qb + (size_t)(b * 2048 + sq) * 1024 + h * 64;
    #pragma unroll
    for (int ks = 0; ks < 2; ++ks) qf[mf][ks] = *(const bf16x8*)(qp + ks * 32 + q4 * 8);
  }

  f32x4 accO[2][4] = {};
  f32x4 lsum[2] = {};
  bf16x8 ones;
  #pragma unroll
  for (int j = 0; j < 8; ++j) ones[j] = (short)0x3F80;   // bf16 1.0

  // per-lane fragment base pointers (advance per chunk); imm offsets cover
  // the ks (+64B) / cb (+64B) pair so each pair shares one address.
  const unsigned short* kp0 = Kb + ((size_t)b * 2048 + r) * 1024 + h * 64 + q4 * 8;
  const unsigned short* kp1 = kp0 + 16 * 1024;
  const unsigned short* kp2 = kp0 + 32 * 1024;
  const unsigned short* kp3 = kp0 + 48 * 1024;
  const unsigned short* vp0 = VT + ((size_t)bh * 64 + r) * 2048 + q4 * 8;
  const unsigned short* vp1 = vp0 + (size_t)16 * 2048;
  const unsigned short* vp2 = vp0 + (size_t)32 * 2048;
  const unsigned short* vp3 = vp0 + (size_t)48 * 2048;
  const float* kqp = ks2 + bh * 2048 + q4 * 4;

  #pragma unroll 2
  for (int c = 0; c < 32; ++c) {
    // K fragments: ka[ks][kfm] = K[c*64 + kfm*16 + r][ks*32 + q4*8 ..]
    bf16x8 ka[2][4], vb[2][4];
    ka[0][0] = *(const bf16x8*)(kp0);      ka[1][0] = *(const bf16x8*)(kp0 + 32);
    ka[0][1] = *(const bf16x8*)(kp1);      ka[1][1] = *(const bf16x8*)(kp1 + 32);
    ka[0][2] = *(const bf16x8*)(kp2);      ka[1][2] = *(const bf16x8*)(kp2 + 32);
    ka[0][3] = *(const bf16x8*)(kp3);      ka[1][3] = *(const bf16x8*)(kp3 + 32);
    // V fragments: vb[cb][df] = VT[bh][df*16+r][c*64 + cb*32 + q4*8 ..]
    vb[0][0] = *(const bf16x8*)(vp0);      vb[1][0] = *(const bf16x8*)(vp0 + 32);
    vb[0][1] = *(const bf16x8*)(vp1);      vb[1][1] = *(const bf16x8*)(vp1 + 32);
    vb[0][2] = *(const bf16x8*)(vp2);      vb[1][2] = *(const bf16x8*)(vp2 + 32);
    vb[0][3] = *(const bf16x8*)(vp3);      vb[1][3] = *(const bf16x8*)(vp3 + 32);
    f32x4 kq[4];
    #pragma unroll
    for (int kfm = 0; kfm < 4; ++kfm) kq[kfm] = *(const f32x4*)(kqp + kfm * 16);

    // S^T = K.Q^T : A=K-frag (m=key), B=Q-frag (n=qrow)
    f32x4 accST[4][2] = {};
    #pragma unroll
    for (int ks = 0; ks < 2; ++ks) {
      #pragma unroll
      for (int kfm = 0; kfm < 4; ++kfm) {
        accST[kfm][0] = __builtin_amdgcn_mfma_f32_16x16x32_bf16(ka[ks][kfm], qf[0][ks], accST[kfm][0], 0, 0, 0);
        accST[kfm][1] = __builtin_amdgcn_mfma_f32_16x16x32_bf16(ka[ks][kfm], qf[1][ks], accST[kfm][1], 0, 0, 0);
      }
    }

    // p = exp2(cc*qk - k2s); trunc-pack to pf[cb][mf] (keys tau(8q4+j))
    bf16x8 pf[2][2];
    #pragma unroll
    for (int cb = 0; cb < 2; ++cb) {
      #pragma unroll
      for (int mf = 0; mf < 2; ++mf) {
        unsigned int dw[4];
        #pragma unroll
        for (int half = 0; half < 2; ++half) {
          int kfm = cb * 2 + half;
          float pp[4];
          #pragma unroll
          for (int i = 0; i < 4; ++i) {
            float u = __builtin_fmaf(cc, accST[kfm][mf][i], -kq[kfm][i]);
            pp[i] = __builtin_amdgcn_exp2f(u);
          }
          dw[half * 2 + 0] = (fbits(pp[0]) >> 16) | (fbits(pp[1]) & 0xFFFF0000u);
          dw[half * 2 + 1] = (fbits(pp[2]) >> 16) | (fbits(pp[3]) & 0xFFFF0000u);
        }
        union { unsigned int d[4]; bf16x8 v; } cv;
        cv.d[0] = dw[0]; cv.d[1] = dw[1]; cv.d[2] = dw[2]; cv.d[3] = dw[3];
        pf[cb][mf] = cv.v;
      }
    }

    // O += P.V ; lsum += P.ones
    #pragma unroll
    for (int cb = 0; cb < 2; ++cb) {
      #pragma unroll
      for (int mf = 0; mf < 2; ++mf)
        lsum[mf] = __builtin_amdgcn_mfma_f32_16x16x32_bf16(pf[cb][mf], ones, lsum[mf], 0, 0, 0);
      #pragma unroll
      for (int df = 0; df < 4; ++df) {
        #pragma unroll
        for (int mf = 0; mf < 2; ++mf)
          accO[mf][df] = __builtin_amdgcn_mfma_f32_16x16x32_bf16(pf[cb][mf], vb[cb][df], accO[mf][df], 0, 0, 0);
      }
    }
    kp0 += 65536; kp1 += 65536; kp2 += 65536; kp3 += 65536;
    vp0 += 64; vp1 += 64; vp2 += 64; vp3 += 64;
    kqp += 64;
  }
  #pragma unroll
  for (int mf = 0; mf < 2; ++mf) {
    float inv[4];
    #pragma unroll
    for (int i = 0; i < 4; ++i) inv[i] = 1.0f / lsum[mf][i];
    #pragma unroll
    for (int df = 0; df < 4; ++df) {
      int d = df * 16 + r;
      #pragma unroll
      for (int i = 0; i < 4; ++i) {
        int sq = q0 + w * 32 + mf * 16 + q4 * 4 + i;
        AO[(size_t)(b * 2048 + sq) * 1024 + h * 64 + d] = f2b(accO[mf][df][i] * inv[i]);
      }
    }
  }
}

// ------------------------------------------------------------- out GEMM
// 128x64 tile, BK=64 two-stage, grid 16x32 = 512 blocks (2/CU).
__global__ __launch_bounds__(256, 2) void gemm_out_kernel(
    const unsigned short* __restrict__ A, const unsigned short* __restrict__ WT,
    const float* __restrict__ bo, float* __restrict__ Out) {
  __shared__ __align__(16) unsigned short As[2 * 128 * 32];   // [kh][row<128][32]
  __shared__ __align__(16) unsigned short Bs[2 * 64 * 32];    // [kh][row<64][32]
  const int t = threadIdx.x, w = t >> 6, lane = t & 63;
  const int r = lane & 15, q4 = lane >> 4;
  const int m0 = blockIdx.y * 128, n0 = blockIdx.x * 64;
  const int wr = (w >> 1) * 64, wc = (w & 1) * 32;
  const unsigned short* Ag = A + (size_t)m0 * 1024;
  const unsigned short* Wg = WT + (size_t)n0 * 1024;
  f32x4 acc[4][2] = {};
  for (int k0 = 0; k0 < 1024; k0 += 64) {
    #pragma unroll
    for (int g = 0; g < 4; ++g) {
      int slot = g * 256 + t;
      int kh = slot >> 9, row = (slot >> 2) & 127, ko = (slot & 3) * 8;
      GLD_LDS(Ag + (size_t)row * 1024 + k0 + kh * 32 + ko, &As[(g * 256 + w * 64) * 8]);
    }
    #pragma unroll
    for (int g = 0; g < 2; ++g) {
      int slot = g * 256 + t;
      int kh = slot >> 8, row = (slot >> 2) & 63, ko = (slot & 3) * 8;
      GLD_LDS(Wg + (size_t)row * 1024 + k0 + kh * 32 + ko, &Bs[(g * 256 + w * 64) * 8]);
    }
    __syncthreads();
    #pragma unroll
    for (int kh = 0; kh < 2; ++kh) {
      bf16x8 af[4], bfr[2];
      #pragma unroll
      for (int mf = 0; mf < 4; ++mf)
        af[mf] = *(const bf16x8*)&As[kh * 4096 + (wr + mf * 16 + r) * 32 + q4 * 8];
      #pragma unroll
      for (int nf = 0; nf < 2; ++nf)
        bfr[nf] = *(const bf16x8*)&Bs[kh * 2048 + (wc + nf * 16 + r) * 32 + q4 * 8];
      #pragma unroll
      for (int mf = 0; mf < 4; ++mf)
        #pragma unroll
        for (int nf = 0; nf < 2; ++nf)
          acc[mf][nf] = __builtin_amdgcn_mfma_f32_16x16x32_bf16(af[mf], bfr[nf], acc[mf][nf], 0, 0, 0);
    }
    __syncthreads();
  }
  #pragma unroll
  for (int nf = 0; nf < 2; ++nf) {
    int n = n0 + wc + nf * 16 + r;
    float bb = bo[n];
    #pragma unroll
    for (int mf = 0; mf < 4; ++mf) {
      int m = m0 + wr + mf * 16 + q4 * 4;
      f32x4 v = acc[mf][nf];
      #pragma unroll
      for (int i = 0; i < 4; ++i)
        Out[(size_t)(m + i) * 1024 + n] = v[i] + bb;
    }
  }
}

// ---------------------------------------------------------------- launch
extern "C" void kernel_launch(void* const* d_in, const int* in_sizes, int n_in,
                              void* d_out, int out_size, void* d_ws, size_t ws_size,
                              hipStream_t stream) {
  const float* X    = (const float*)d_in[0];
  const float* wq   = (const float*)d_in[1];
  const float* bq   = (const float*)d_in[2];
  const float* wk   = (const float*)d_in[3];
  const float* bk   = (const float*)d_in[4];
  const float* wv   = (const float*)d_in[5];
  const float* bv   = (const float*)d_in[6];
  const float* wo   = (const float*)d_in[7];
  const float* bo   = (const float*)d_in[8];
  const float* temp = (const float*)d_in[9];
  float* Out = (float*)d_out;

  char* ws = (char*)d_ws;
  unsigned short* Xb    = (unsigned short*)ws; ws += (size_t)4096 * 1024 * 2;
  unsigned short* WTqkv = (unsigned short*)ws; ws += (size_t)3072 * 1024 * 2;
  unsigned short* WTo   = (unsigned short*)ws; ws += (size_t)1024 * 1024 * 2;
  unsigned short* Qb    = (unsigned short*)ws; ws += (size_t)4096 * 1024 * 2;
  unsigned short* Kb    = (unsigned short*)ws; ws += (size_t)4096 * 1024 * 2;
  unsigned short* VT    = (unsigned short*)ws; ws += (size_t)4096 * 1024 * 2;
  float* ks2 = (float*)ws; ws += (size_t)65536 * 4;
  unsigned short* AO = Xb;   // Xb dead after gemm_qkv; reuse for flash output

  prep_kernel<<<dim3(16, 16, 5), 256, 0, stream>>>(X, wq, wk, wv, wo, Xb, WTqkv, WTo);
  gemm_qkv_kernel<<<dim3(24, 32), 256, 0, stream>>>(Xb, WTqkv, bq, bk, bv, temp, Qb, Kb, VT, ks2);
  flash_kernel<<<dim3(16, 32), 256, 0, stream>>>(Qb, Kb, VT, ks2, temp, AO);
  gemm_out_kernel<<<dim3(16, 32), 256, 0, stream>>>(AO, WTo, bo, Out);
}

// Round 9
// 197.790 us; speedup vs baseline: 1.4527x; 1.4527x over previous
//
#include <hip/hip_runtime.h>
#include <stdint.h>
#include <stddef.h>

// EuclideanAttention MI355X, round 9.
// - flash: r6's exact 256-thread staging/LDS structure, but 64 q-rows per
//   block (mf removed, each wave 16 rows), grid (32,32)=1024 blocks,
//   __launch_bounds__(256,4) -> 4 blocks/CU = 4 independent barrier domains,
//   16 waves/CU. (r8's 128-thread variant crashed; this re-expresses the
//   experiment in the proven 256-thread shape.)
// - GEMMs + prep: identical to r7 (passed, residual ~136.5 us).

#define LOG2E 1.44269504088896f

typedef __attribute__((ext_vector_type(8))) short bf16x8;
typedef __attribute__((ext_vector_type(4))) float f32x4;
typedef __attribute__((ext_vector_type(4))) unsigned short u16x4;

__device__ __forceinline__ unsigned short f2b(float f) {
  union { float f; unsigned int u; } x; x.f = f;
  unsigned int u = x.u;
  u += 0x7fffu + ((u >> 16) & 1u);   // RNE
  return (unsigned short)(u >> 16);
}
__device__ __forceinline__ float b2f(unsigned short s) {
  union { unsigned int u; float f; } x; x.u = ((unsigned int)s) << 16;
  return x.f;
}
__device__ __forceinline__ unsigned int fbits(float f) {
  union { float f; unsigned int u; } x; x.f = f; return x.u;
}

// async global->LDS, 16B per lane. LDS dest = wave-uniform base + lane*16.
#define GLD_LDS(g, l) __builtin_amdgcn_global_load_lds( \
    (const __attribute__((address_space(1))) void*)(g), \
    (__attribute__((address_space(3))) void*)(l), 16, 0, 0)

// ------------------------------------------------- prep: W transpose + X cvt
__global__ void prep_kernel(const float* __restrict__ X,
                            const float* __restrict__ wq, const float* __restrict__ wk,
                            const float* __restrict__ wv, const float* __restrict__ wo,
                            unsigned short* __restrict__ Xb,
                            unsigned short* __restrict__ WTqkv, unsigned short* __restrict__ WTo) {
  int z = blockIdx.z;
  if (z == 4) {
    size_t base = ((size_t)(blockIdx.y * 16 + blockIdx.x)) * 16384;
    #pragma unroll
    for (int j = 0; j < 16; ++j) {
      size_t i = base + (size_t)(j * 256 + threadIdx.x) * 4;
      f32x4 v = *(const f32x4*)&X[i];
      u16x4 o;
      #pragma unroll
      for (int k = 0; k < 4; ++k) o[k] = f2b(v[k]);
      *(u16x4*)&Xb[i] = o;
    }
    return;
  }
  __shared__ float tile[64][65];
  const float* src = (z == 0) ? wq : (z == 1) ? wk : (z == 2) ? wv : wo;
  unsigned short* dst = (z < 3) ? (WTqkv + (size_t)z * 1024 * 1024) : WTo;
  int k0 = blockIdx.y * 64, n0 = blockIdx.x * 64;
  int rr = threadIdx.x >> 6, cc = threadIdx.x & 63;
  #pragma unroll
  for (int p = 0; p < 16; ++p) {
    int row = p * 4 + rr;
    tile[row][cc] = src[(size_t)(k0 + row) * 1024 + n0 + cc];
  }
  __syncthreads();
  #pragma unroll
  for (int p = 0; p < 16; ++p) {
    int row = p * 4 + rr;                       // n offset
    dst[(size_t)(n0 + row) * 1024 + k0 + cc] = f2b(tile[cc][row]);
  }
}

// -------------------------------------------------------------- QKV GEMM
// C[4096,3072] = X @ [wq|wk|wv] + bias. 128x128 tile, BK=64 two-stage,
// 3 blocks/CU. K epilogue emits pre-scaled ||row||^2 (* log2e/T). V epilogue
// LDS-transposes into permuted VT (pos = G*32+q4*8+sub*4+i) with coalesced writes.
__global__ __launch_bounds__(256, 3) void gemm_qkv_kernel(
    const unsigned short* __restrict__ X, const unsigned short* __restrict__ WT,
    const float* __restrict__ bq, const float* __restrict__ bk, const float* __restrict__ bv,
    const float* __restrict__ temp,
    unsigned short* __restrict__ Qb, unsigned short* __restrict__ Kb,
    unsigned short* __restrict__ VTo, float* __restrict__ ks2) {
  __shared__ __align__(16) unsigned short smem[16896];   // As(8192) Bs(8192) | Vt alias
  unsigned short* As = smem;            // [kh<2][row<128][32]
  unsigned short* Bs = smem + 8192;
  const int t = threadIdx.x, w = t >> 6, lane = t & 63;
  const int r = lane & 15, q4 = lane >> 4;
  const int m0 = blockIdx.y * 128, n0 = blockIdx.x * 128;
  const int wr = (w >> 1) * 64, wc = (w & 1) * 64;
  const unsigned short* Xg = X + (size_t)m0 * 1024;
  const unsigned short* Wg = WT + (size_t)n0 * 1024;
  f32x4 acc[4][4] = {};
  for (int k0 = 0; k0 < 1024; k0 += 64) {
    #pragma unroll
    for (int g = 0; g < 4; ++g) {
      int slot = g * 256 + t;
      int kh = slot >> 9, row = (slot >> 2) & 127, ko = (slot & 3) * 8;
      GLD_LDS(Xg + (size_t)row * 1024 + k0 + kh * 32 + ko, &As[(g * 256 + w * 64) * 8]);
      GLD_LDS(Wg + (size_t)row * 1024 + k0 + kh * 32 + ko, &Bs[(g * 256 + w * 64) * 8]);
    }
    __syncthreads();
    #pragma unroll
    for (int kh = 0; kh < 2; ++kh) {
      bf16x8 af[4], bfr[4];
      #pragma unroll
      for (int mf = 0; mf < 4; ++mf)
        af[mf] = *(const bf16x8*)&As[kh * 4096 + (wr + mf * 16 + r) * 32 + q4 * 8];
      #pragma unroll
      for (int nf = 0; nf < 4; ++nf)
        bfr[nf] = *(const bf16x8*)&Bs[kh * 4096 + (wc + nf * 16 + r) * 32 + q4 * 8];
      #pragma unroll
      for (int mf = 0; mf < 4; ++mf)
        #pragma unroll
        for (int nf = 0; nf < 4; ++nf)
          acc[mf][nf] = __builtin_amdgcn_mfma_f32_16x16x32_bf16(af[mf], bfr[nf], acc[mf][nf], 0, 0, 0);
    }
    __syncthreads();
  }
  const int nblk = n0 >> 10;
  if (nblk == 0) {
    // Q: plain bf16 store (q^2 shift cancels in softmax)
    const int nc0 = n0 & 1023;
    #pragma unroll
    for (int nf = 0; nf < 4; ++nf) {
      int n = nc0 + wc + nf * 16 + r;
      float bb = bq[n];
      #pragma unroll
      for (int mf = 0; mf < 4; ++mf) {
        int m = m0 + wr + mf * 16 + q4 * 4;
        f32x4 v = acc[mf][nf];
        #pragma unroll
        for (int i = 0; i < 4; ++i)
          Qb[(size_t)(m + i) * 1024 + n] = f2b(v[i] + bb);
      }
    }
  } else if (nblk == 1) {
    const float sc = LOG2E / temp[0];
    const int nc0 = n0 & 1023;
    float s2a[4][4] = {};
    #pragma unroll
    for (int nf = 0; nf < 4; ++nf) {
      int n = nc0 + wc + nf * 16 + r;
      float bb = bk[n];
      #pragma unroll
      for (int mf = 0; mf < 4; ++mf) {
        int m = m0 + wr + mf * 16 + q4 * 4;
        f32x4 v = acc[mf][nf];
        #pragma unroll
        for (int i = 0; i < 4; ++i) {
          unsigned short os = f2b(v[i] + bb);
          Kb[(size_t)(m + i) * 1024 + n] = os;
          float xb = b2f(os);
          s2a[mf][i] += xb * xb;          // sum of squares of the ROUNDED value
        }
      }
    }
    #pragma unroll
    for (int mf = 0; mf < 4; ++mf)
      #pragma unroll
      for (int i = 0; i < 4; ++i) {
        float v = s2a[mf][i];
        v += __shfl_xor(v, 1, 64);
        v += __shfl_xor(v, 2, 64);
        v += __shfl_xor(v, 4, 64);
        v += __shfl_xor(v, 8, 64);
        s2a[mf][i] = v * sc;
      }
    if (r == 0) {
      int hh = (nc0 + wc) >> 6;
      #pragma unroll
      for (int mf = 0; mf < 4; ++mf) {
        int m = m0 + wr + mf * 16 + q4 * 4;
        int bb2 = m >> 11, ss = m & 2047;
        #pragma unroll
        for (int i = 0; i < 4; ++i)
          ks2[(size_t)(bb2 * 16 + hh) * 2048 + ss + i] = s2a[mf][i];
      }
    }
  } else {
    // ---- V: LDS transpose -> permuted, coalesced VT writes (Vt aliases As/Bs)
    unsigned short* Vt = smem;          // [head<2][d<64][G<2 * pos<64], stride 132
    const int c0 = n0 - 2048;
    const int head = w & 1;             // == wc>>6
    #pragma unroll
    for (int nf = 0; nf < 4; ++nf) {
      int c = c0 + wc + nf * 16 + r;
      float bb = bv[c];
      int d = c & 63;
      #pragma unroll
      for (int mf = 0; mf < 4; ++mf) {
        int mloc = wr + mf * 16 + q4 * 4;     // 0..124
        int G = mloc >> 6;
        int k6 = mloc & 63;
        int pos = (k6 >> 5) * 32 + ((k6 & 15) >> 2) * 8 + ((k6 >> 4) & 1) * 4;
        f32x4 v = acc[mf][nf];
        u16x4 pk;
        #pragma unroll
        for (int i = 0; i < 4; ++i) pk[i] = f2b(v[i] + bb);
        *(u16x4*)&Vt[(head * 64 + d) * 132 + G * 64 + pos] = pk;
      }
    }
    __syncthreads();
    int row = t >> 1, ch = t & 1;
    int hd = row >> 6, dd = row & 63;
    int hglob = (c0 >> 6) + hd;
    int bb2 = m0 >> 11, s0 = m0 & 2047;
    unsigned short* dst = &VTo[((size_t)((bb2 * 16 + hglob) * 64 + dd)) * 2048 + s0 + ch * 64];
    const unsigned short* srcL = &Vt[(hd * 64 + dd) * 132 + ch * 64];
    #pragma unroll
    for (int k2 = 0; k2 < 16; ++k2)
      *(u16x4*)&dst[k2 * 4] = *(const u16x4*)&srcL[k2 * 4];
  }
}

// ---------------------------------------------------------------- flash
// Block = (bh, 64 q-rows), 4 waves x 16 rows, grid (32,32)=1024 blocks ->
// 4 blocks/CU (16 waves/CU, 4 independent barrier domains). 64-key
// double-buffered chunks; staging identical to r6 (256-thread slot math).
// S^T = K.Q^T: C-frag doubles as PV A-operand (keys tau-permuted); VT is
// pre-permuted so a PV B-frag is one ds_read_b128 from the XOR-swizzled stage.
// p = exp2((2qk - k^2)*log2e/T)  (q^2 shift cancels; bounded by ~8)
__global__ __launch_bounds__(256, 4) void flash_kernel(
    const unsigned short* __restrict__ Qb, const unsigned short* __restrict__ Kb,
    const unsigned short* __restrict__ VT, const float* __restrict__ ks2,
    const float* __restrict__ temp, unsigned short* __restrict__ AO) {
  __shared__ __align__(16) unsigned short Ks[2][64 * 64];   // [buf][khalf<2][key<64][dd<32]
  __shared__ __align__(16) unsigned short Vs[2][64 * 64];   // [buf] XOR-swizzled 16B units
  const int t = threadIdx.x, w = t >> 6, lane = t & 63;
  const int r = lane & 15, q4 = lane >> 4;
  const int bh = blockIdx.y, b = bh >> 4, h = bh & 15;
  const int q0 = blockIdx.x * 64;
  const float cc = 2.0f * LOG2E / temp[0];

  // Q fragment (B-operand: n=qrow=lane&15, k=q4*8+j); wave w owns rows q0+w*16..+15
  bf16x8 qf[2];
  {
    int sq = q0 + w * 16 + r;
    const unsigned short* qp = Qb + (size_t)(b * 2048 + sq) * 1024 + h * 64;
    #pragma unroll
    for (int ks = 0; ks < 2; ++ks) qf[ks] = *(const bf16x8*)(qp + ks * 32 + q4 * 8);
  }

  f32x4 accO[4] = {};
  f32x4 lsum = {};
  bf16x8 ones;
  #pragma unroll
  for (int j = 0; j < 8; ++j) ones[j] = (short)0x3F80;   // bf16 1.0

  const unsigned short* Kg = Kb + ((size_t)b * 2048) * 1024 + h * 64;
  const unsigned short* Vg = VT + ((size_t)bh * 64) * 2048;
  const float* kqb = ks2 + bh * 2048;

  // per-lane staging sources (identical to r6; advance per chunk)
  const unsigned short* kp0 = Kg + (size_t)(t >> 2) * 1024 + (t & 3) * 8;  // khalf 0
  const unsigned short* kp1 = kp0 + 32;                                    // khalf 1
  int dd0 = t >> 3;
  const unsigned short* vp0 = Vg + (size_t)dd0 * 2048 + ((t & 7) ^ (dd0 & 7)) * 8;
  const unsigned short* vp1 = vp0 + (size_t)32 * 2048;
  GLD_LDS(kp0, &Ks[0][t * 8]);
  GLD_LDS(kp1, &Ks[0][(256 + t) * 8]);
  GLD_LDS(vp0, &Vs[0][t * 8]);
  GLD_LDS(vp1, &Vs[0][(256 + t) * 8]);
  kp0 += 65536; kp1 += 65536; vp0 += 64; vp1 += 64;

  #pragma unroll 2
  for (int c = 0; c < 32; ++c) {
    const int buf = c & 1;
    __syncthreads();                    // drains stage(c) (flew during compute(c-1))
    if (c < 31) {
      GLD_LDS(kp0, &Ks[buf ^ 1][t * 8]);
      GLD_LDS(kp1, &Ks[buf ^ 1][(256 + t) * 8]);
      GLD_LDS(vp0, &Vs[buf ^ 1][t * 8]);
      GLD_LDS(vp1, &Vs[buf ^ 1][(256 + t) * 8]);
      kp0 += 65536; kp1 += 65536; vp0 += 64; vp1 += 64;
    }
    // k^2 (pre-scaled) for this chunk; latency hidden under the S^T MFMAs
    f32x4 kq[4];
    #pragma unroll
    for (int kfm = 0; kfm < 4; ++kfm)
      kq[kfm] = *(const f32x4*)&kqb[c * 64 + kfm * 16 + q4 * 4];

    // S^T = K.Q^T : A=K-frag (m=key), B=Q-frag (n=qrow)
    f32x4 accST[4] = {};
    #pragma unroll
    for (int ks = 0; ks < 2; ++ks) {
      #pragma unroll
      for (int kfm = 0; kfm < 4; ++kfm) {
        bf16x8 ka = *(const bf16x8*)&Ks[buf][(ks * 64 + kfm * 16 + r) * 32 + q4 * 8];
        accST[kfm] = __builtin_amdgcn_mfma_f32_16x16x32_bf16(ka, qf[ks], accST[kfm], 0, 0, 0);
      }
    }

    // p = exp2(cc*qk - k2s); trunc-pack to pf[cb] (keys tau(8q4+j))
    bf16x8 pf[2];
    #pragma unroll
    for (int cb = 0; cb < 2; ++cb) {
      unsigned int dw[4];
      #pragma unroll
      for (int half = 0; half < 2; ++half) {
        int kfm = cb * 2 + half;
        float pp[4];
        #pragma unroll
        for (int i = 0; i < 4; ++i) {
          float u = __builtin_fmaf(cc, accST[kfm][i], -kq[kfm][i]);
          pp[i] = __builtin_amdgcn_exp2f(u);
        }
        dw[half * 2 + 0] = (fbits(pp[0]) >> 16) | (fbits(pp[1]) & 0xFFFF0000u);
        dw[half * 2 + 1] = (fbits(pp[2]) >> 16) | (fbits(pp[3]) & 0xFFFF0000u);
      }
      union { unsigned int d[4]; bf16x8 v; } cv;
      cv.d[0] = dw[0]; cv.d[1] = dw[1]; cv.d[2] = dw[2]; cv.d[3] = dw[3];
      pf[cb] = cv.v;
    }

    // O += P.V ; lsum += P.ones  (B-frag = one b128 from swizzled Vs)
    #pragma unroll
    for (int cb = 0; cb < 2; ++cb) {
      lsum = __builtin_amdgcn_mfma_f32_16x16x32_bf16(pf[cb], ones, lsum, 0, 0, 0);
      #pragma unroll
      for (int df = 0; df < 4; ++df) {
        int dloc = df * 16 + r;
        int un = dloc * 8 + ((cb * 4 + q4) ^ (dloc & 7));
        bf16x8 vb = *(const bf16x8*)&Vs[buf][un * 8];
        accO[df] = __builtin_amdgcn_mfma_f32_16x16x32_bf16(pf[cb], vb, accO[df], 0, 0, 0);
      }
    }
  }
  {
    float inv[4];
    #pragma unroll
    for (int i = 0; i < 4; ++i) inv[i] = 1.0f / lsum[i];
    #pragma unroll
    for (int df = 0; df < 4; ++df) {
      int d = df * 16 + r;
      #pragma unroll
      for (int i = 0; i < 4; ++i) {
        int sq = q0 + w * 16 + q4 * 4 + i;
        AO[(size_t)(b * 2048 + sq) * 1024 + h * 64 + d] = f2b(accO[df][i] * inv[i]);
      }
    }
  }
}

// ------------------------------------------------------------- out GEMM
// 128x64 tile, BK=64 two-stage, grid 16x32 = 512 blocks (2/CU).
__global__ __launch_bounds__(256, 2) void gemm_out_kernel(
    const unsigned short* __restrict__ A, const unsigned short* __restrict__ WT,
    const float* __restrict__ bo, float* __restrict__ Out) {
  __shared__ __align__(16) unsigned short As[2 * 128 * 32];   // [kh][row<128][32]
  __shared__ __align__(16) unsigned short Bs[2 * 64 * 32];    // [kh][row<64][32]
  const int t = threadIdx.x, w = t >> 6, lane = t & 63;
  const int r = lane & 15, q4 = lane >> 4;
  const int m0 = blockIdx.y * 128, n0 = blockIdx.x * 64;
  const int wr = (w >> 1) * 64, wc = (w & 1) * 32;
  const unsigned short* Ag = A + (size_t)m0 * 1024;
  const unsigned short* Wg = WT + (size_t)n0 * 1024;
  f32x4 acc[4][2] = {};
  for (int k0 = 0; k0 < 1024; k0 += 64) {
    #pragma unroll
    for (int g = 0; g < 4; ++g) {
      int slot = g * 256 + t;
      int kh = slot >> 9, row = (slot >> 2) & 127, ko = (slot & 3) * 8;
      GLD_LDS(Ag + (size_t)row * 1024 + k0 + kh * 32 + ko, &As[(g * 256 + w * 64) * 8]);
    }
    #pragma unroll
    for (int g = 0; g < 2; ++g) {
      int slot = g * 256 + t;
      int kh = slot >> 8, row = (slot >> 2) & 63, ko = (slot & 3) * 8;
      GLD_LDS(Wg + (size_t)row * 1024 + k0 + kh * 32 + ko, &Bs[(g * 256 + w * 64) * 8]);
    }
    __syncthreads();
    #pragma unroll
    for (int kh = 0; kh < 2; ++kh) {
      bf16x8 af[4], bfr[2];
      #pragma unroll
      for (int mf = 0; mf < 4; ++mf)
        af[mf] = *(const bf16x8*)&As[kh * 4096 + (wr + mf * 16 + r) * 32 + q4 * 8];
      #pragma unroll
      for (int nf = 0; nf < 2; ++nf)
        bfr[nf] = *(const bf16x8*)&Bs[kh * 2048 + (wc + nf * 16 + r) * 32 + q4 * 8];
      #pragma unroll
      for (int mf = 0; mf < 4; ++mf)
        #pragma unroll
        for (int nf = 0; nf < 2; ++nf)
          acc[mf][nf] = __builtin_amdgcn_mfma_f32_16x16x32_bf16(af[mf], bfr[nf], acc[mf][nf], 0, 0, 0);
    }
    __syncthreads();
  }
  #pragma unroll
  for (int nf = 0; nf < 2; ++nf) {
    int n = n0 + wc + nf * 16 + r;
    float bb = bo[n];
    #pragma unroll
    for (int mf = 0; mf < 4; ++mf) {
      int m = m0 + wr + mf * 16 + q4 * 4;
      f32x4 v = acc[mf][nf];
      #pragma unroll
      for (int i = 0; i < 4; ++i)
        Out[(size_t)(m + i) * 1024 + n] = v[i] + bb;
    }
  }
}

// ---------------------------------------------------------------- launch
extern "C" void kernel_launch(void* const* d_in, const int* in_sizes, int n_in,
                              void* d_out, int out_size, void* d_ws, size_t ws_size,
                              hipStream_t stream) {
  const float* X    = (const float*)d_in[0];
  const float* wq   = (const float*)d_in[1];
  const float* bq   = (const float*)d_in[2];
  const float* wk   = (const float*)d_in[3];
  const float* bk   = (const float*)d_in[4];
  const float* wv   = (const float*)d_in[5];
  const float* bv   = (const float*)d_in[6];
  const float* wo   = (const float*)d_in[7];
  const float* bo   = (const float*)d_in[8];
  const float* temp = (const float*)d_in[9];
  float* Out = (float*)d_out;

  char* ws = (char*)d_ws;
  unsigned short* Xb    = (unsigned short*)ws; ws += (size_t)4096 * 1024 * 2;
  unsigned short* WTqkv = (unsigned short*)ws; ws += (size_t)3072 * 1024 * 2;
  unsigned short* WTo   = (unsigned short*)ws; ws += (size_t)1024 * 1024 * 2;
  unsigned short* Qb    = (unsigned short*)ws; ws += (size_t)4096 * 1024 * 2;
  unsigned short* Kb    = (unsigned short*)ws; ws += (size_t)4096 * 1024 * 2;
  unsigned short* VT    = (unsigned short*)ws; ws += (size_t)4096 * 1024 * 2;
  float* ks2 = (float*)ws; ws += (size_t)65536 * 4;
  unsigned short* AO = Xb;   // Xb dead after gemm_qkv; reuse for flash output

  prep_kernel<<<dim3(16, 16, 5), 256, 0, stream>>>(X, wq, wk, wv, wo, Xb, WTqkv, WTo);
  gemm_qkv_kernel<<<dim3(24, 32), 256, 0, stream>>>(Xb, WTqkv, bq, bk, bv, temp, Qb, Kb, VT, ks2);
  flash_kernel<<<dim3(32, 32), 256, 0, stream>>>(Qb, Kb, VT, ks2, temp, AO);
  gemm_out_kernel<<<dim3(16, 32), 256, 0, stream>>>(AO, WTo, bo, Out);
}